// Round 5
// baseline (595.628 us; speedup 1.0000x reference)
//
#include <hip/hip_runtime.h>
#include <hip/hip_bf16.h>

#define N_FEAT 8192
#define D_MODEL 256
#define HEADS 4
#define CELLS 32
#define BATCH 4096
#define HC 128          // HEADS*CELLS
#define NT 16           // n-rows per reps block
#define DC 64           // d-chunk
#define KSPLIT 16
#define KCH (N_FEAT / KSPLIT)   // 512

typedef unsigned int u32;
typedef __attribute__((ext_vector_type(8))) short bf16x8;
typedef __attribute__((ext_vector_type(4))) float f32x4;

__device__ __forceinline__ unsigned short f32_to_bf16(float f) {
    union { float f; unsigned u; } v; v.f = f;
    unsigned r = v.u + 0x7fffu + ((v.u >> 16) & 1u);
    return (unsigned short)(r >> 16);
}

__device__ __forceinline__ float bf16_to_f32(unsigned short h) {
    union { unsigned u; float f; } v; v.u = ((unsigned)h) << 16;
    return v.f;
}

__device__ __forceinline__ unsigned pack_bf16x2(float lo, float hi) {
    return (unsigned)f32_to_bf16(lo) | ((unsigned)f32_to_bf16(hi) << 16);
}

// async DMA global->LDS, 4 B per lane; LDS dest = base + lane*4 (wave-uniform base)
__device__ __forceinline__ void async_cp4(const void* g, u32* l) {
    __builtin_amdgcn_global_load_lds(
        (const __attribute__((address_space(1))) u32*)g,
        (__attribute__((address_space(3))) u32*)l, 4, 0, 0);
}

// ---------------------------------------------------------------------------
// Stage 1 (fused): tropical scores -> top-2 -> sigmoid blend -> reps + repsT
// ---------------------------------------------------------------------------
__global__ __launch_bounds__(256) void reps_kernel(
    const float* __restrict__ proj, const float* __restrict__ rw,
    const float* __restrict__ rb, const float* __restrict__ cb,
    unsigned short* __restrict__ reps_bf, unsigned short* __restrict__ repsT)
{
    __shared__ float latS[NT][DC + 4];
    __shared__ float wS[HC][DC + 4];
    __shared__ float sc[NT][HC + 4];
    __shared__ float gateS[NT][HEADS];
    __shared__ int   widxS[NT][HEADS], ridxS[NT][HEADS];

    const int t = threadIdx.x;
    const int nbase = blockIdx.x * NT;
    const int tx = t & 31, ty = t >> 5;

    float acc[2][4];
    #pragma unroll
    for (int i = 0; i < 2; ++i)
        #pragma unroll
        for (int j = 0; j < 4; ++j)
            acc[i][j] = -3.4e38f;

    for (int dk = 0; dk < D_MODEL; dk += DC) {
        __syncthreads();
        {
            const int row = t >> 4, c4 = t & 15;
            float4 v = *(const float4*)&proj[(long)(nbase + row) * D_MODEL + dk + c4 * 4];
            *(float4*)&latS[row][c4 * 4] = v;
        }
        {
            int f = t;
            #pragma unroll
            for (int i = 0; i < 8; ++i, f += 256) {
                const int row = f >> 4, c4 = f & 15;
                float4 v = *(const float4*)&rw[(long)row * D_MODEL + dk + c4 * 4];
                *(float4*)&wS[row][c4 * 4] = v;
            }
        }
        __syncthreads();

        #pragma unroll 4
        for (int d = 0; d < DC; d += 4) {
            float4 la[2], wv[4];
            #pragma unroll
            for (int i = 0; i < 2; ++i) la[i] = *(const float4*)&latS[ty + 8 * i][d];
            #pragma unroll
            for (int j = 0; j < 4; ++j) wv[j] = *(const float4*)&wS[tx + 32 * j][d];
            #pragma unroll
            for (int i = 0; i < 2; ++i)
                #pragma unroll
                for (int j = 0; j < 4; ++j) {
                    float m01 = fmaxf(la[i].x + wv[j].x, la[i].y + wv[j].y);
                    float m23 = fmaxf(la[i].z + wv[j].z, la[i].w + wv[j].w);
                    acc[i][j] = fmaxf(acc[i][j], fmaxf(m01, m23));
                }
        }
    }

    #pragma unroll
    for (int j = 0; j < 4; ++j) {
        const float rbv = rb[tx + 32 * j];
        #pragma unroll
        for (int i = 0; i < 2; ++i)
            sc[ty + 8 * i][tx + 32 * j] = acc[i][j] + rbv;
    }
    __syncthreads();

    if (t < NT * HEADS) {
        const int n = t >> 2, h = t & 3;
        float v1 = -3.4e38f, v2 = -3.4e38f; int i1 = 0, i2 = 0;
        #pragma unroll
        for (int c = 0; c < CELLS; ++c) {
            float s = sc[n][h * CELLS + c];
            if (s > v1) { v2 = v1; i2 = i1; v1 = s; i1 = c; }
            else if (s > v2) { v2 = s; i2 = c; }
        }
        gateS[n][h] = 1.0f / (1.0f + __expf(-(v1 - v2)));
        widxS[n][h] = i1; ridxS[n][h] = i2;
    }
    __syncthreads();

    float vals[NT];
    #pragma unroll
    for (int r = 0; r < NT; ++r)
        vals[r] = proj[(long)(nbase + r) * D_MODEL + t];
    #pragma unroll
    for (int h = 0; h < HEADS; ++h) {
        #pragma unroll
        for (int r = 0; r < NT; ++r) {
            const float g = gateS[r][h];
            const float wv = cb[(long)(h * CELLS + widxS[r][h]) * D_MODEL + t];
            const float rv = cb[(long)(h * CELLS + ridxS[r][h]) * D_MODEL + t];
            vals[r] += g * wv + (1.0f - g) * rv;   // CODE_SCALE = 1
        }
    }
    #pragma unroll
    for (int r = 0; r < NT; ++r)
        reps_bf[(long)(nbase + r) * D_MODEL + t] = f32_to_bf16(vals[r]);
    unsigned pk[NT / 2];
    #pragma unroll
    for (int i = 0; i < NT / 2; ++i)
        pk[i] = pack_bf16x2(vals[2 * i], vals[2 * i + 1]);
    uint4* dst = (uint4*)(repsT + (long)t * N_FEAT + nbase);
    dst[0] = *(const uint4*)&pk[0];
    dst[1] = *(const uint4*)&pk[4];
}

// ---------------------------------------------------------------------------
// Stage 2: hidden partials, tile 128m x 256n (full N), BK=32, K-split x16.
// A (x, f32) + B (repsT, bf16) staged via async global_load_lds size-4 with
// per-group padding (all frag reads 2-way = free). A converted f32->bf16 at
// fragment read. Partials stored bf16 in MFMA-native layout: every wave
// store is 512 B lane-contiguous (no partial-line amplification).
// ---------------------------------------------------------------------------
__global__ __launch_bounds__(256, 4) void gemm1_kernel(
    const float* __restrict__ x, const unsigned short* __restrict__ repsT,
    uint2* __restrict__ hid_prt)
{
    // A: 64 pair-groups, each = 2 m-rows x 32 k f32 (256 B) + 16 B pad
    // B: 64 quad-groups, each = 4 n-rows x 32 k bf16 (256 B) + 16 B pad
    __shared__ __align__(16) u32 Asm[64 * 68];
    __shared__ __align__(16) u32 Bsm[64 * 68];

    const int by = blockIdx.x;          // m-tile 0..31
    const int ks = blockIdx.y;          // k-split 0..15
    const int m0 = by * 128;
    const int t = threadIdx.x;
    const int wave = t >> 6, lane = t & 63;
    const int quad = lane >> 4, l16 = lane & 15;

    f32x4 acc[8][4];
    #pragma unroll
    for (int i = 0; i < 8; ++i)
        #pragma unroll
        for (int j = 0; j < 4; ++j)
            acc[i][j] = (f32x4){0.f, 0.f, 0.f, 0.f};

    const int kbeg = ks * KCH;

    for (int it = 0; it < KCH / 32; ++it) {   // 16 iters
        const int k0 = kbeg + it * 32;
        __syncthreads();
        #pragma unroll
        for (int ii = 0; ii < 16; ++ii) {     // A: 64 insts across 4 waves
            const int g = wave * 16 + ii;
            const float* gp = x + (long)(m0 + 2 * g + (lane >> 5)) * N_FEAT
                                + k0 + (lane & 31);
            async_cp4(gp, &Asm[g * 68]);
        }
        #pragma unroll
        for (int ii = 0; ii < 16; ++ii) {     // B: 64 insts across 4 waves
            const int g = wave * 16 + ii;
            const unsigned short* gp = repsT + (long)(4 * g + (lane >> 4)) * N_FEAT
                                             + k0 + (lane & 15) * 2;
            async_cp4(gp, &Bsm[g * 68]);
        }
        __syncthreads();

        bf16x8 bfr[4];
        #pragma unroll
        for (int j = 0; j < 4; ++j) {
            const int n = wave * 64 + j * 16 + l16;
            const char* p = (const char*)Bsm + (n >> 2) * 272 + (n & 3) * 64 + quad * 16;
            bfr[j] = *(const bf16x8*)p;
        }
        #pragma unroll
        for (int i = 0; i < 8; ++i) {
            const int m = i * 16 + l16;
            const char* p = (const char*)Asm + (m >> 1) * 272 + (m & 1) * 128 + quad * 32;
            float4 a0 = *(const float4*)p;
            float4 a1 = *(const float4*)(p + 16);
            union { unsigned u[4]; bf16x8 v; } af;
            af.u[0] = pack_bf16x2(a0.x, a0.y); af.u[1] = pack_bf16x2(a0.z, a0.w);
            af.u[2] = pack_bf16x2(a1.x, a1.y); af.u[3] = pack_bf16x2(a1.z, a1.w);
            #pragma unroll
            for (int j = 0; j < 4; ++j)
                acc[i][j] = __builtin_amdgcn_mfma_f32_16x16x32_bf16(
                    af.v, bfr[j], acc[i][j], 0, 0, 0);
        }
    }

    // native-layout bf16 partial store: slot = ((by*4+wave)*32 + f)*64 + lane
    uint2* hp = hid_prt + (long)ks * 262144;
    #pragma unroll
    for (int i = 0; i < 8; ++i)
        #pragma unroll
        for (int j = 0; j < 4; ++j) {
            const int f = i * 4 + j;
            const long slot = (((long)(by * 4 + wave)) * 32 + f) * 64 + lane;
            uint2 v;
            v.x = pack_bf16x2(acc[i][j][0], acc[i][j][1]);
            v.y = pack_bf16x2(acc[i][j][2], acc[i][j][3]);
            hp[slot] = v;
        }
}

// ---------------------------------------------------------------------------
// Stage 2b: sum 16 native-layout bf16 slices, un-permute, write hid_bf
// ---------------------------------------------------------------------------
__global__ __launch_bounds__(256) void reduce_kernel(
    const uint2* __restrict__ hp, unsigned short* __restrict__ hb)
{
    const int s = blockIdx.x * 256 + threadIdx.x;   // 262144 slots
    float sum[4] = {0.f, 0.f, 0.f, 0.f};
    #pragma unroll
    for (int k = 0; k < KSPLIT; ++k) {
        uint2 v = hp[(long)k * 262144 + s];
        sum[0] += bf16_to_f32((unsigned short)(v.x & 0xffff));
        sum[1] += bf16_to_f32((unsigned short)(v.x >> 16));
        sum[2] += bf16_to_f32((unsigned short)(v.y & 0xffff));
        sum[3] += bf16_to_f32((unsigned short)(v.y >> 16));
    }
    const int lane = s & 63, f = (s >> 6) & 31, wave = (s >> 11) & 3, by = s >> 13;
    const int i = f >> 2, j = f & 3, quad = lane >> 4, l16 = lane & 15;
    const int col = wave * 64 + j * 16 + l16;
    const int row0 = by * 128 + i * 16 + quad * 4;
    #pragma unroll
    for (int r = 0; r < 4; ++r)
        hb[(long)(row0 + r) * D_MODEL + col] = f32_to_bf16(sum[r]);
}

// ---------------------------------------------------------------------------
// Stage 3: out = relu(hidden @ reps^T + bias). 128x128 tile, BK=32, 8 iters,
// async LDS staging; epilogue via LDS transpose -> full 512 B row writes.
// ---------------------------------------------------------------------------
__global__ __launch_bounds__(256, 4) void gemm2_kernel(
    const unsigned short* __restrict__ hb, const unsigned short* __restrict__ reps,
    const float* __restrict__ bias, float* __restrict__ out)
{
    __shared__ __align__(16) union {
        struct { u32 a[32 * 68]; u32 b[32 * 68]; } s;   // 2 x 8704 B staging
        float c[64][130];                               // 33280 B C-transpose
    } sm;

    const int m0 = blockIdx.y * 128;   // batch
    const int n0 = blockIdx.x * 128;   // features
    const int t = threadIdx.x;
    const int wave = t >> 6, lane = t & 63;
    const int wm = (wave >> 1) * 64, wn = (wave & 1) * 64;
    const int quad = lane >> 4, l16 = lane & 15;

    f32x4 acc[4][4];
    #pragma unroll
    for (int i = 0; i < 4; ++i)
        #pragma unroll
        for (int j = 0; j < 4; ++j)
            acc[i][j] = (f32x4){0.f, 0.f, 0.f, 0.f};

    const float4 bias4 = *(const float4*)&bias[n0 + (lane & 31) * 4];

    for (int it = 0; it < D_MODEL / 32; ++it) {   // 8 iters
        const int k0 = it * 32;
        __syncthreads();
        #pragma unroll
        for (int ii = 0; ii < 8; ++ii) {          // A + B: 32+32 insts
            const int g = wave * 8 + ii;
            const unsigned short* ga = hb + (long)(m0 + 4 * g + (lane >> 4)) * D_MODEL
                                          + k0 + (lane & 15) * 2;
            async_cp4(ga, &sm.s.a[g * 68]);
            const unsigned short* gb = reps + (long)(n0 + 4 * g + (lane >> 4)) * D_MODEL
                                            + k0 + (lane & 15) * 2;
            async_cp4(gb, &sm.s.b[g * 68]);
        }
        __syncthreads();

        bf16x8 af[4], bfr[4];
        #pragma unroll
        for (int i = 0; i < 4; ++i) {
            const int m = wm + i * 16 + l16;
            const char* p = (const char*)sm.s.a + (m >> 2) * 272 + (m & 3) * 64 + quad * 16;
            af[i] = *(const bf16x8*)p;
        }
        #pragma unroll
        for (int j = 0; j < 4; ++j) {
            const int n = wn + j * 16 + l16;
            const char* p = (const char*)sm.s.b + (n >> 2) * 272 + (n & 3) * 64 + quad * 16;
            bfr[j] = *(const bf16x8*)p;
        }
        #pragma unroll
        for (int i = 0; i < 4; ++i)
            #pragma unroll
            for (int j = 0; j < 4; ++j)
                acc[i][j] = __builtin_amdgcn_mfma_f32_16x16x32_bf16(
                    af[i], bfr[j], acc[i][j], 0, 0, 0);
    }

    // epilogue: 2 half-tiles of 64 rows through LDS, coalesced 512 B rows
    #pragma unroll
    for (int h = 0; h < 2; ++h) {
        __syncthreads();
        if ((wave >> 1) == h) {
            #pragma unroll
            for (int i = 0; i < 4; ++i)
                #pragma unroll
                for (int j = 0; j < 4; ++j)
                    #pragma unroll
                    for (int r = 0; r < 4; ++r)
                        sm.c[i * 16 + quad * 4 + r][wn + j * 16 + l16] = acc[i][j][r];
        }
        __syncthreads();
        #pragma unroll
        for (int ii = 0; ii < 8; ++ii) {
            const int r2 = wave * 16 + 2 * ii + (lane >> 5);
            float4 v = *(const float4*)&sm.c[r2][(lane & 31) * 4];
            v.x = fmaxf(v.x + bias4.x, 0.f);
            v.y = fmaxf(v.y + bias4.y, 0.f);
            v.z = fmaxf(v.z + bias4.z, 0.f);
            v.w = fmaxf(v.w + bias4.w, 0.f);
            *(float4*)&out[(long)(m0 + h * 64 + r2) * N_FEAT + n0 + (lane & 31) * 4] = v;
        }
    }
}

// ---------------------------------------------------------------------------
extern "C" void kernel_launch(void* const* d_in, const int* in_sizes, int n_in,
                              void* d_out, int out_size, void* d_ws, size_t ws_size,
                              hipStream_t stream) {
    const float* x    = (const float*)d_in[0];
    const float* proj = (const float*)d_in[1];
    const float* rw   = (const float*)d_in[2];
    const float* rb   = (const float*)d_in[3];
    const float* cb   = (const float*)d_in[4];
    const float* bias = (const float*)d_in[5];
    float* out = (float*)d_out;

    char* ws = (char*)d_ws;
    unsigned short* reps_bf = (unsigned short*)ws;                 // 4 MB
    unsigned short* repsT   = (unsigned short*)(ws + (4u << 20));  // 4 MB
    uint2* hid_prt          = (uint2*)(ws + (8u << 20));           // 32 MB (16 x 2 MB)
    unsigned short* hid_bf  = (unsigned short*)(ws + (40u << 20)); // 2 MB

    reps_kernel<<<N_FEAT / NT, 256, 0, stream>>>(proj, rw, rb, cb, reps_bf, repsT);
    gemm1_kernel<<<dim3(32, KSPLIT), 256, 0, stream>>>(x, repsT, hid_prt);
    reduce_kernel<<<1024, 256, 0, stream>>>(hid_prt, hid_bf);
    gemm2_kernel<<<dim3(64, 32), 256, 0, stream>>>(hid_bf, reps_bf, bias, out);
}

// Round 6
// 370.918 us; speedup vs baseline: 1.6058x; 1.6058x over previous
//
#include <hip/hip_runtime.h>
#include <hip/hip_bf16.h>

#define N_FEAT 8192
#define D_MODEL 256
#define HEADS 4
#define CELLS 32
#define BATCH 4096
#define HC 128          // HEADS*CELLS
#define NT 16           // n-rows per reps block
#define DC 64           // d-chunk
#define KSPLIT 16
#define KCH (N_FEAT / KSPLIT)   // 512

typedef unsigned int u32;
typedef __attribute__((ext_vector_type(8))) short bf16x8;
typedef __attribute__((ext_vector_type(4))) float f32x4;

__device__ __forceinline__ unsigned short f32_to_bf16(float f) {
    union { float f; unsigned u; } v; v.f = f;
    unsigned r = v.u + 0x7fffu + ((v.u >> 16) & 1u);
    return (unsigned short)(r >> 16);
}

__device__ __forceinline__ float bf16_to_f32(unsigned short h) {
    union { unsigned u; float f; } v; v.u = ((unsigned)h) << 16;
    return v.f;
}

__device__ __forceinline__ unsigned pack_bf16x2(float lo, float hi) {
    return (unsigned)f32_to_bf16(lo) | ((unsigned)f32_to_bf16(hi) << 16);
}

// async DMA global->LDS, 4 B per lane; LDS dest = wave-uniform base + lane*4
__device__ __forceinline__ void async_cp4(const void* g, u32* l) {
    __builtin_amdgcn_global_load_lds(
        (const __attribute__((address_space(1))) u32*)g,
        (__attribute__((address_space(3))) u32*)l, 4, 0, 0);
}

// ---------------------------------------------------------------------------
// Stage 1 (fused): tropical scores -> top-2 -> sigmoid blend -> reps + repsT
// ---------------------------------------------------------------------------
__global__ __launch_bounds__(256) void reps_kernel(
    const float* __restrict__ proj, const float* __restrict__ rw,
    const float* __restrict__ rb, const float* __restrict__ cb,
    unsigned short* __restrict__ reps_bf, unsigned short* __restrict__ repsT)
{
    __shared__ float latS[NT][DC + 4];
    __shared__ float wS[HC][DC + 4];
    __shared__ float sc[NT][HC + 4];
    __shared__ float gateS[NT][HEADS];
    __shared__ int   widxS[NT][HEADS], ridxS[NT][HEADS];

    const int t = threadIdx.x;
    const int nbase = blockIdx.x * NT;
    const int tx = t & 31, ty = t >> 5;

    float acc[2][4];
    #pragma unroll
    for (int i = 0; i < 2; ++i)
        #pragma unroll
        for (int j = 0; j < 4; ++j)
            acc[i][j] = -3.4e38f;

    for (int dk = 0; dk < D_MODEL; dk += DC) {
        __syncthreads();
        {
            const int row = t >> 4, c4 = t & 15;
            float4 v = *(const float4*)&proj[(long)(nbase + row) * D_MODEL + dk + c4 * 4];
            *(float4*)&latS[row][c4 * 4] = v;
        }
        {
            int f = t;
            #pragma unroll
            for (int i = 0; i < 8; ++i, f += 256) {
                const int row = f >> 4, c4 = f & 15;
                float4 v = *(const float4*)&rw[(long)row * D_MODEL + dk + c4 * 4];
                *(float4*)&wS[row][c4 * 4] = v;
            }
        }
        __syncthreads();

        #pragma unroll 4
        for (int d = 0; d < DC; d += 4) {
            float4 la[2], wv[4];
            #pragma unroll
            for (int i = 0; i < 2; ++i) la[i] = *(const float4*)&latS[ty + 8 * i][d];
            #pragma unroll
            for (int j = 0; j < 4; ++j) wv[j] = *(const float4*)&wS[tx + 32 * j][d];
            #pragma unroll
            for (int i = 0; i < 2; ++i)
                #pragma unroll
                for (int j = 0; j < 4; ++j) {
                    float m01 = fmaxf(la[i].x + wv[j].x, la[i].y + wv[j].y);
                    float m23 = fmaxf(la[i].z + wv[j].z, la[i].w + wv[j].w);
                    acc[i][j] = fmaxf(acc[i][j], fmaxf(m01, m23));
                }
        }
    }

    #pragma unroll
    for (int j = 0; j < 4; ++j) {
        const float rbv = rb[tx + 32 * j];
        #pragma unroll
        for (int i = 0; i < 2; ++i)
            sc[ty + 8 * i][tx + 32 * j] = acc[i][j] + rbv;
    }
    __syncthreads();

    if (t < NT * HEADS) {
        const int n = t >> 2, h = t & 3;
        float v1 = -3.4e38f, v2 = -3.4e38f; int i1 = 0, i2 = 0;
        #pragma unroll
        for (int c = 0; c < CELLS; ++c) {
            float s = sc[n][h * CELLS + c];
            if (s > v1) { v2 = v1; i2 = i1; v1 = s; i1 = c; }
            else if (s > v2) { v2 = s; i2 = c; }
        }
        gateS[n][h] = 1.0f / (1.0f + __expf(-(v1 - v2)));
        widxS[n][h] = i1; ridxS[n][h] = i2;
    }
    __syncthreads();

    float vals[NT];
    #pragma unroll
    for (int r = 0; r < NT; ++r)
        vals[r] = proj[(long)(nbase + r) * D_MODEL + t];
    #pragma unroll
    for (int h = 0; h < HEADS; ++h) {
        #pragma unroll
        for (int r = 0; r < NT; ++r) {
            const float g = gateS[r][h];
            const float wv = cb[(long)(h * CELLS + widxS[r][h]) * D_MODEL + t];
            const float rv = cb[(long)(h * CELLS + ridxS[r][h]) * D_MODEL + t];
            vals[r] += g * wv + (1.0f - g) * rv;   // CODE_SCALE = 1
        }
    }
    #pragma unroll
    for (int r = 0; r < NT; ++r)
        reps_bf[(long)(nbase + r) * D_MODEL + t] = f32_to_bf16(vals[r]);
    unsigned pk[NT / 2];
    #pragma unroll
    for (int i = 0; i < NT / 2; ++i)
        pk[i] = pack_bf16x2(vals[2 * i], vals[2 * i + 1]);
    uint4* dst = (uint4*)(repsT + (long)t * N_FEAT + nbase);
    dst[0] = *(const uint4*)&pk[0];
    dst[1] = *(const uint4*)&pk[4];
}

// ---------------------------------------------------------------------------
// Stage 2: hidden partials. 128x128 tile (4x4 acc = 64 VGPR — fits, no spill),
// BK=32, K-split x16, async global_load_lds staging (no staging VGPRs).
// A kept f32 in LDS, converted f32->bf16 at fragment read.
// Partials stored bf16 in MFMA-native layout (512 B lane-contiguous bursts).
// ---------------------------------------------------------------------------
__global__ __launch_bounds__(256, 3) void gemm1_kernel(
    const float* __restrict__ x, const unsigned short* __restrict__ repsT,
    uint2* __restrict__ hid_prt)
{
    // A: 64 groups of 2 m-rows x 32 f32 (256 B) + 16 B pad
    // B: 32 groups of 4 n-rows x 32 bf16 (64 B/row) + 16 B pad
    __shared__ __align__(16) u32 Asm[64 * 68];
    __shared__ __align__(16) u32 Bsm[32 * 68];

    const int bx = blockIdx.x;          // n-tile 0..1
    const int by = blockIdx.y;          // m-tile 0..31
    const int ks = blockIdx.z;          // k-split 0..15
    const int m0 = by * 128;
    const int n0 = bx * 128;
    const int t = threadIdx.x;
    const int wave = t >> 6, lane = t & 63;
    const int wm = (wave >> 1) * 64, wn = (wave & 1) * 64;
    const int quad = lane >> 4, l16 = lane & 15;

    f32x4 acc[4][4];
    #pragma unroll
    for (int i = 0; i < 4; ++i)
        #pragma unroll
        for (int j = 0; j < 4; ++j)
            acc[i][j] = (f32x4){0.f, 0.f, 0.f, 0.f};

    const int kbeg = ks * KCH;

    for (int it = 0; it < KCH / 32; ++it) {   // 16 iters
        const int k0 = kbeg + it * 32;
        __syncthreads();
        #pragma unroll
        for (int ii = 0; ii < 16; ++ii) {     // A: 64 wave-insts over 4 waves
            const int g = wave * 16 + ii;
            const float* gp = x + (long)(m0 + 2 * g + (lane >> 5)) * N_FEAT
                                + k0 + (lane & 31);
            async_cp4(gp, &Asm[g * 68]);
        }
        #pragma unroll
        for (int ii = 0; ii < 8; ++ii) {      // B: 32 wave-insts over 4 waves
            const int g = wave * 8 + ii;
            const unsigned short* gp = repsT + (long)(n0 + 4 * g + (lane >> 4)) * N_FEAT
                                             + k0 + (lane & 15) * 2;
            async_cp4(gp, &Bsm[g * 68]);
        }
        __syncthreads();

        bf16x8 bfr[4];
        #pragma unroll
        for (int j = 0; j < 4; ++j) {
            const int n = wn + j * 16 + l16;
            const char* p = (const char*)Bsm + (n >> 2) * 272 + (n & 3) * 64 + quad * 16;
            bfr[j] = *(const bf16x8*)p;
        }
        #pragma unroll
        for (int i = 0; i < 4; ++i) {
            const int m = wm + i * 16 + l16;
            const char* p = (const char*)Asm + (m >> 1) * 272 + (m & 1) * 128 + quad * 32;
            float4 a0 = *(const float4*)p;
            float4 a1 = *(const float4*)(p + 16);
            union { unsigned u[4]; bf16x8 v; } af;
            af.u[0] = pack_bf16x2(a0.x, a0.y); af.u[1] = pack_bf16x2(a0.z, a0.w);
            af.u[2] = pack_bf16x2(a1.x, a1.y); af.u[3] = pack_bf16x2(a1.z, a1.w);
            #pragma unroll
            for (int j = 0; j < 4; ++j)
                acc[i][j] = __builtin_amdgcn_mfma_f32_16x16x32_bf16(
                    af.v, bfr[j], acc[i][j], 0, 0, 0);
        }
    }

    // native-layout bf16 partial store: 512 B lane-contiguous per (wave,frag)
    const int bl = by * 2 + bx;               // 0..63
    uint2* hp = hid_prt + (long)ks * 262144;
    #pragma unroll
    for (int i = 0; i < 4; ++i)
        #pragma unroll
        for (int j = 0; j < 4; ++j) {
            const int f = i * 4 + j;
            const long slot = (((long)bl * 4 + wave) * 16 + f) * 64 + lane;
            uint2 v;
            v.x = pack_bf16x2(acc[i][j][0], acc[i][j][1]);
            v.y = pack_bf16x2(acc[i][j][2], acc[i][j][3]);
            hp[slot] = v;
        }
}

// ---------------------------------------------------------------------------
// Stage 2b: sum 16 native-layout bf16 slices, un-permute, write hid_bf
// ---------------------------------------------------------------------------
__global__ __launch_bounds__(256) void reduce_kernel(
    const uint2* __restrict__ hp, unsigned short* __restrict__ hb)
{
    const int s = blockIdx.x * 256 + threadIdx.x;   // 262144 slots
    float sum[4] = {0.f, 0.f, 0.f, 0.f};
    #pragma unroll
    for (int k = 0; k < KSPLIT; ++k) {
        uint2 v = hp[(long)k * 262144 + s];
        sum[0] += bf16_to_f32((unsigned short)(v.x & 0xffff));
        sum[1] += bf16_to_f32((unsigned short)(v.x >> 16));
        sum[2] += bf16_to_f32((unsigned short)(v.y & 0xffff));
        sum[3] += bf16_to_f32((unsigned short)(v.y >> 16));
    }
    const int lane = s & 63, f = (s >> 6) & 15, wave = (s >> 10) & 3, bl = s >> 12;
    const int by = bl >> 1, bx = bl & 1;
    const int i = f >> 2, j = f & 3, quad = lane >> 4, l16 = lane & 15;
    const int col = bx * 128 + (wave & 1) * 64 + j * 16 + l16;
    const int row0 = by * 128 + (wave >> 1) * 64 + i * 16 + quad * 4;
    #pragma unroll
    for (int r = 0; r < 4; ++r)
        hb[(long)(row0 + r) * D_MODEL + col] = f32_to_bf16(sum[r]);
}

// ---------------------------------------------------------------------------
// Stage 3: out = relu(hidden @ reps^T + bias). 128x128 tile, BK=32, 8 iters,
// async LDS staging; epilogue via LDS transpose -> full 512 B row writes.
// ---------------------------------------------------------------------------
__global__ __launch_bounds__(256, 4) void gemm2_kernel(
    const unsigned short* __restrict__ hb, const unsigned short* __restrict__ reps,
    const float* __restrict__ bias, float* __restrict__ out)
{
    __shared__ __align__(16) union {
        struct { u32 a[32 * 68]; u32 b[32 * 68]; } s;   // 2 x 8704 B staging
        float c[64][130];                               // 33280 B C-transpose
    } sm;

    const int m0 = blockIdx.y * 128;   // batch
    const int n0 = blockIdx.x * 128;   // features
    const int t = threadIdx.x;
    const int wave = t >> 6, lane = t & 63;
    const int wm = (wave >> 1) * 64, wn = (wave & 1) * 64;
    const int quad = lane >> 4, l16 = lane & 15;

    f32x4 acc[4][4];
    #pragma unroll
    for (int i = 0; i < 4; ++i)
        #pragma unroll
        for (int j = 0; j < 4; ++j)
            acc[i][j] = (f32x4){0.f, 0.f, 0.f, 0.f};

    const float4 bias4 = *(const float4*)&bias[n0 + (lane & 31) * 4];

    for (int it = 0; it < D_MODEL / 32; ++it) {   // 8 iters
        const int k0 = it * 32;
        __syncthreads();
        #pragma unroll
        for (int ii = 0; ii < 8; ++ii) {          // A + B: 32+32 insts
            const int g = wave * 8 + ii;
            const unsigned short* ga = hb + (long)(m0 + 4 * g + (lane >> 4)) * D_MODEL
                                          + k0 + (lane & 15) * 2;
            async_cp4(ga, &sm.s.a[g * 68]);
            const unsigned short* gb = reps + (long)(n0 + 4 * g + (lane >> 4)) * D_MODEL
                                            + k0 + (lane & 15) * 2;
            async_cp4(gb, &sm.s.b[g * 68]);
        }
        __syncthreads();

        bf16x8 af[4], bfr[4];
        #pragma unroll
        for (int i = 0; i < 4; ++i) {
            const int m = wm + i * 16 + l16;
            const char* p = (const char*)sm.s.a + (m >> 2) * 272 + (m & 3) * 64 + quad * 16;
            af[i] = *(const bf16x8*)p;
        }
        #pragma unroll
        for (int j = 0; j < 4; ++j) {
            const int n = wn + j * 16 + l16;
            const char* p = (const char*)sm.s.b + (n >> 2) * 272 + (n & 3) * 64 + quad * 16;
            bfr[j] = *(const bf16x8*)p;
        }
        #pragma unroll
        for (int i = 0; i < 4; ++i)
            #pragma unroll
            for (int j = 0; j < 4; ++j)
                acc[i][j] = __builtin_amdgcn_mfma_f32_16x16x32_bf16(
                    af[i], bfr[j], acc[i][j], 0, 0, 0);
    }

    // epilogue: 2 half-tiles of 64 rows through LDS, coalesced 512 B rows
    #pragma unroll
    for (int h = 0; h < 2; ++h) {
        __syncthreads();
        if ((wave >> 1) == h) {
            #pragma unroll
            for (int i = 0; i < 4; ++i)
                #pragma unroll
                for (int j = 0; j < 4; ++j)
                    #pragma unroll
                    for (int r = 0; r < 4; ++r)
                        sm.c[i * 16 + quad * 4 + r][wn + j * 16 + l16] = acc[i][j][r];
        }
        __syncthreads();
        #pragma unroll
        for (int ii = 0; ii < 8; ++ii) {
            const int r2 = wave * 16 + 2 * ii + (lane >> 5);
            float4 v = *(const float4*)&sm.c[r2][(lane & 31) * 4];
            v.x = fmaxf(v.x + bias4.x, 0.f);
            v.y = fmaxf(v.y + bias4.y, 0.f);
            v.z = fmaxf(v.z + bias4.z, 0.f);
            v.w = fmaxf(v.w + bias4.w, 0.f);
            *(float4*)&out[(long)(m0 + h * 64 + r2) * N_FEAT + n0 + (lane & 31) * 4] = v;
        }
    }
}

// ---------------------------------------------------------------------------
extern "C" void kernel_launch(void* const* d_in, const int* in_sizes, int n_in,
                              void* d_out, int out_size, void* d_ws, size_t ws_size,
                              hipStream_t stream) {
    const float* x    = (const float*)d_in[0];
    const float* proj = (const float*)d_in[1];
    const float* rw   = (const float*)d_in[2];
    const float* rb   = (const float*)d_in[3];
    const float* cb   = (const float*)d_in[4];
    const float* bias = (const float*)d_in[5];
    float* out = (float*)d_out;

    char* ws = (char*)d_ws;
    unsigned short* reps_bf = (unsigned short*)ws;                 // 4 MB
    unsigned short* repsT   = (unsigned short*)(ws + (4u << 20));  // 4 MB
    uint2* hid_prt          = (uint2*)(ws + (8u << 20));           // 32 MB (16 x 2 MB)
    unsigned short* hid_bf  = (unsigned short*)(ws + (40u << 20)); // 2 MB

    reps_kernel<<<N_FEAT / NT, 256, 0, stream>>>(proj, rw, rb, cb, reps_bf, repsT);
    gemm1_kernel<<<dim3(2, 32, KSPLIT), 256, 0, stream>>>(x, repsT, hid_prt);
    reduce_kernel<<<1024, 256, 0, stream>>>(hid_prt, hid_bf);
    gemm2_kernel<<<dim3(64, 32), 256, 0, stream>>>(hid_bf, reps_bf, bias, out);
}